// Round 1
// baseline (657.826 us; speedup 1.0000x reference)
//
#include <hip/hip_runtime.h>
#include <hip/hip_bf16.h>

// MultiHeadAttention S=1024 B=4 D=1024 H=16 DH=64
// Pipeline: [1] qkv_proj (3x GEMM 4096x1024x1024, f32->bf16, per-head W)
//           [2] attn (per (b,h,16-q-row-tile): QK^T -> mask -> softmax fp32 -> PV)
//           [3] out_proj (GEMM 4096x1024x1024, bf16 A, f32 Wo)
// ws layout (bf16): q[4096*1024] @0, k @8MB, v @16MB, attn_out @24MB  (32MB total)

typedef __attribute__((ext_vector_type(8))) short short8;
typedef __attribute__((ext_vector_type(4))) float f32x4;
typedef __attribute__((ext_vector_type(8))) __bf16 bf16x8;

union B8 {
    short8 s;
    bf16x8 b;
    unsigned short u[8];
};

static __device__ __forceinline__ unsigned short f2bf_rne(float f) {
    union { float f; unsigned u; } v; v.f = f;
    unsigned r = v.u + 0x7FFFu + ((v.u >> 16) & 1u);
    return (unsigned short)(r >> 16);
}

// ---------------------------------------------------------------------------
// GEMM body: C[4096 x 64cols] = A[4096,1024] * B[1024, 64 (pitch bpitch)] + bias
// 64x64 tile per block, BK=32, 256 threads (4 waves, one 16-row strip each).
// ---------------------------------------------------------------------------
template <bool A_F32, bool OUT_F32>
__device__ __forceinline__ void gemm_body(const void* __restrict__ Av,
                                          const float* __restrict__ B,
                                          const float* __restrict__ bias,
                                          void* __restrict__ Cv,
                                          int bpitch, int col0) {
    constexpr int PAD = 40;  // bf16 elems per row: 80B pitch -> 16B aligned, 2-way-bank-free
    __shared__ unsigned short sA[64 * PAD];   // A tile [64 rows][32 k]
    __shared__ unsigned short sBt[64 * PAD];  // B tile transposed [64 n][32 k]

    const int t = threadIdx.x;
    const int wave = t >> 6;
    const int lane = t & 63;
    const int quad = lane >> 4;
    const int l15 = lane & 15;
    const int row0 = blockIdx.y * 64;

    f32x4 acc[4] = {};

    const int a_row = t >> 2;  // 0..63
    const int a_seg = t & 3;   // 0..3 (8 f32 each)
    const int b_row = t >> 3;  // 0..31
    const int b_seg = t & 7;   // 0..7

    for (int k0 = 0; k0 < 1024; k0 += 32) {
        // --- stage A tile ---
        if constexpr (A_F32) {
            const float* A = (const float*)Av;
            const float* src = &A[(size_t)(row0 + a_row) * 1024 + k0 + a_seg * 8];
            f32x4 v0 = *(const f32x4*)src;
            f32x4 v1 = *(const f32x4*)(src + 4);
            B8 w;
#pragma unroll
            for (int j = 0; j < 4; ++j) {
                w.u[j] = f2bf_rne(v0[j]);
                w.u[4 + j] = f2bf_rne(v1[j]);
            }
            *(short8*)&sA[a_row * PAD + a_seg * 8] = w.s;
        } else {
            const unsigned short* A = (const unsigned short*)Av;
            short8 vv = *(const short8*)&A[(size_t)(row0 + a_row) * 1024 + k0 + a_seg * 8];
            *(short8*)&sA[a_row * PAD + a_seg * 8] = vv;
        }
        // --- stage B tile (transposed) ---
        {
            const float* src = &B[(size_t)(k0 + b_row) * bpitch + b_seg * 8];
            f32x4 v0 = *(const f32x4*)src;
            f32x4 v1 = *(const f32x4*)(src + 4);
#pragma unroll
            for (int j = 0; j < 4; ++j) {
                sBt[(b_seg * 8 + j) * PAD + b_row] = f2bf_rne(v0[j]);
                sBt[(b_seg * 8 + 4 + j) * PAD + b_row] = f2bf_rne(v1[j]);
            }
        }
        __syncthreads();
        // --- MFMA ---
        B8 af;
        af.s = *(const short8*)&sA[(wave * 16 + l15) * PAD + quad * 8];
#pragma unroll
        for (int j = 0; j < 4; ++j) {
            B8 bf;
            bf.s = *(const short8*)&sBt[(j * 16 + l15) * PAD + quad * 8];
            acc[j] = __builtin_amdgcn_mfma_f32_16x16x32_bf16(af.b, bf.b, acc[j], 0, 0, 0);
        }
        __syncthreads();
    }
    // --- epilogue: C row = quad*4+r (in strip), col = lane&15 ---
#pragma unroll
    for (int j = 0; j < 4; ++j) {
        int cl = j * 16 + l15;
        float bb = bias[cl];
#pragma unroll
        for (int r = 0; r < 4; ++r) {
            int grow = row0 + wave * 16 + quad * 4 + r;
            size_t idx = (size_t)grow * 1024 + col0 + cl;
            float val = acc[j][r] + bb;
            if constexpr (OUT_F32)
                ((float*)Cv)[idx] = val;
            else
                ((unsigned short*)Cv)[idx] = f2bf_rne(val);
        }
    }
}

__global__ __launch_bounds__(256) void qkv_proj(
    const float* __restrict__ Q, const float* __restrict__ Kx, const float* __restrict__ Vx,
    const float* __restrict__ Wq, const float* __restrict__ Wk, const float* __restrict__ Wv,
    const float* __restrict__ bq, const float* __restrict__ bk, const float* __restrict__ bv,
    unsigned short* q_o, unsigned short* k_o, unsigned short* v_o) {
    const int h = blockIdx.x;
    const int p = blockIdx.z;
    const float* A = (p == 0) ? Q : (p == 1 ? Kx : Vx);
    const float* W = ((p == 0) ? Wq : (p == 1 ? Wk : Wv)) + (size_t)h * 1024 * 64;
    const float* bias = ((p == 0) ? bq : (p == 1 ? bk : bv)) + h * 64;
    unsigned short* C = (p == 0) ? q_o : (p == 1 ? k_o : v_o);
    gemm_body<true, false>(A, W, bias, C, 64, h * 64);
}

__global__ __launch_bounds__(256) void out_proj(const unsigned short* __restrict__ A,
                                                const float* __restrict__ Wo,
                                                const float* __restrict__ bo,
                                                float* __restrict__ C) {
    const int ct = blockIdx.x;
    gemm_body<false, true>(A, Wo + ct * 64, bo + ct * 64, C, 1024, ct * 64);
}

// ---------------------------------------------------------------------------
// Attention: one block = one (b,h) x 16 q-rows. 4 waves.
// Phase 1: each wave computes S[16, 256-col chunk] via MFMA, mask+scale -> LDS fp32
// Phase 2: softmax fp32 over the 1024-row in LDS (exp stored unnormalized, row sums in sL)
// Phase 3: PV, V chunk-staged transposed in LDS; each wave owns a 16-wide dh tile.
// ---------------------------------------------------------------------------
__global__ __launch_bounds__(256) void attn_kernel(
    const unsigned short* __restrict__ q,   // [S,B,H,64] bf16
    const unsigned short* __restrict__ k,
    const unsigned short* __restrict__ v,
    const int* __restrict__ key_mask,       // [S,B] int32 in {0,1}
    unsigned short* __restrict__ o) {       // [S,B,H,64] bf16
    constexpr int SP = 1028;  // fp32 pitch (+4: 16B-aligned rows, 2-way-bank-free)
    constexpr int VP = 264;   // bf16 pitch (+8: 16B-aligned rows)
    __shared__ float sS[16 * SP];            // 65792 B
    __shared__ unsigned short sVt[64 * VP];  // 33792 B
    __shared__ float sL[16];

    const int t = threadIdx.x;
    const int wave = t >> 6;
    const int lane = t & 63;
    const int quad = lane >> 4;
    const int l15 = lane & 15;
    const int qt = blockIdx.x;  // 0..63
    const int b = blockIdx.y;   // 0..3
    const int h = blockIdx.z;   // 0..15
    const int q0 = qt * 16;

    // Q fragments (same for all waves): A[m=lane&15][kk=quad*8+j]
    const unsigned short* qbase = q + ((size_t)q0 * 4 + b) * 1024 + h * 64;
    B8 af0, af1;
    af0.s = *(const short8*)(qbase + (size_t)l15 * 4096 + quad * 8);
    af1.s = *(const short8*)(qbase + (size_t)l15 * 4096 + 32 + quad * 8);

    // --- Phase 1: QK^T, wave w covers k-cols [w*256, w*256+256) ---
    const unsigned short* kbase = k + (size_t)b * 1024 + h * 64;
#pragma unroll 4
    for (int tile = 0; tile < 16; ++tile) {
        const int kcol0 = wave * 256 + tile * 16;
        const unsigned short* kr = kbase + (size_t)(kcol0 + l15) * 4096;
        B8 bf0, bf1;
        bf0.s = *(const short8*)(kr + quad * 8);
        bf1.s = *(const short8*)(kr + 32 + quad * 8);
        f32x4 s4 = {};
        s4 = __builtin_amdgcn_mfma_f32_16x16x32_bf16(af0.b, bf0.b, s4, 0, 0, 0);
        s4 = __builtin_amdgcn_mfma_f32_16x16x32_bf16(af1.b, bf1.b, s4, 0, 0, 0);
        const float m = (float)key_mask[(size_t)(kcol0 + l15) * 4 + b] * 1e18f;
#pragma unroll
        for (int r = 0; r < 4; ++r)
            sS[(quad * 4 + r) * SP + kcol0 + l15] = s4[r] * 0.125f - m;
    }
    __syncthreads();

    // --- Phase 2: softmax per q-row; 16 threads per row (in-wave 16-lane groups) ---
    {
        const int row = t >> 4;  // 0..15
        const int sub = t & 15;
        float m = -1e30f;
        for (int c = sub; c < 1024; c += 16) m = fmaxf(m, sS[row * SP + c]);
#pragma unroll
        for (int off = 8; off; off >>= 1) m = fmaxf(m, __shfl_xor(m, off));
        float l = 0.f;
        for (int c = sub; c < 1024; c += 16) {
            float p = __expf(sS[row * SP + c] - m);
            sS[row * SP + c] = p;
            l += p;
        }
#pragma unroll
        for (int off = 8; off; off >>= 1) l += __shfl_xor(l, off);
        if (sub == 0) sL[row] = l;
    }

    // --- Phase 3: O = P V ; wave w owns dh-tile [16w, 16w+16) ---
    f32x4 oacc = {};
    for (int c = 0; c < 4; ++c) {
        __syncthreads();  // sVt reuse guard (also orders first iter after softmax)
        const unsigned short* vbase = v + ((size_t)(c * 256) * 4 + b) * 1024 + h * 64;
#pragma unroll
        for (int p = 0; p < 8; ++p) {
            const int il = p * 32 + (t >> 3);  // 0..255 (local sk)
            const int seg = t & 7;
            B8 vv;
            vv.s = *(const short8*)(vbase + (size_t)il * 4096 + seg * 8);
#pragma unroll
            for (int j = 0; j < 8; ++j)
                sVt[(seg * 8 + j) * VP + il] = vv.u[j];
        }
        __syncthreads();
#pragma unroll
        for (int kc = 0; kc < 8; ++kc) {
            const f32x4* ps = (const f32x4*)&sS[l15 * SP + c * 256 + kc * 32 + quad * 8];
            f32x4 p0 = ps[0], p1 = ps[1];
            B8 pa;
#pragma unroll
            for (int j = 0; j < 4; ++j) {
                pa.u[j] = f2bf_rne(p0[j]);
                pa.u[4 + j] = f2bf_rne(p1[j]);
            }
            B8 bv_;
            bv_.s = *(const short8*)&sVt[(wave * 16 + l15) * VP + kc * 32 + quad * 8];
            oacc = __builtin_amdgcn_mfma_f32_16x16x32_bf16(pa.b, bv_.b, oacc, 0, 0, 0);
        }
    }
    // --- epilogue: row = quad*4+r, col = lane&15 within wave's dh tile ---
    unsigned short* obase = o + ((size_t)q0 * 4 + b) * 1024 + h * 64 + wave * 16;
#pragma unroll
    for (int r = 0; r < 4; ++r) {
        const int row = quad * 4 + r;
        const float val = oacc[r] / sL[row];
        obase[(size_t)row * 4096 + l15] = f2bf_rne(val);
    }
}

extern "C" void kernel_launch(void* const* d_in, const int* in_sizes, int n_in,
                              void* d_out, int out_size, void* d_ws, size_t ws_size,
                              hipStream_t stream) {
    const float* query = (const float*)d_in[0];
    const float* key_ = (const float*)d_in[1];
    const float* value = (const float*)d_in[2];
    const int* key_mask = (const int*)d_in[3];
    const float* Wq = (const float*)d_in[4];
    const float* bq = (const float*)d_in[5];
    const float* Wk = (const float*)d_in[6];
    const float* bk = (const float*)d_in[7];
    const float* Wv = (const float*)d_in[8];
    const float* bv = (const float*)d_in[9];
    const float* Wo = (const float*)d_in[10];
    const float* bo = (const float*)d_in[11];
    float* out = (float*)d_out;

    const size_t NE = (size_t)4096 * 1024;
    unsigned short* q_ws = (unsigned short*)d_ws;
    unsigned short* k_ws = q_ws + NE;
    unsigned short* v_ws = k_ws + NE;
    unsigned short* a_ws = v_ws + NE;

    qkv_proj<<<dim3(16, 64, 3), 256, 0, stream>>>(query, key_, value, Wq, Wk, Wv,
                                                  bq, bk, bv, q_ws, k_ws, v_ws);
    attn_kernel<<<dim3(64, 4, 16), 256, 0, stream>>>(q_ws, k_ws, v_ws, key_mask, a_ws);
    out_proj<<<dim3(16, 64, 1), 256, 0, stream>>>(a_ws, Wo, bo, out);
}

// Round 2
// 378.775 us; speedup vs baseline: 1.7367x; 1.7367x over previous
//
#include <hip/hip_runtime.h>
#include <hip/hip_bf16.h>

// MultiHeadAttention S=1024 B=4 D=1024 H=16 DH=64
// [1] qkv_proj (3x GEMM 4096x1024x1024, f32->bf16, per-head W)  (unchanged this round)
// [2] attn: flash-style, block = (b,h) x 128 q-rows, 4 waves x 32 q.
//     S^T = K·Q^T via mfma_32x32x16_bf16 (Q frags in regs); softmax w/o max
//     (bounded scores, mask folded in multiplicatively via ballot bitmask);
//     P chains in-register into mfma_32x32x8bf16_1k for O = P·V.
// [3] out_proj (GEMM, unchanged)
// ws (bf16): q @0, k @8MB, v @16MB, attn_out @24MB

typedef __attribute__((ext_vector_type(8))) short short8;
typedef __attribute__((ext_vector_type(4))) short short4_;
typedef __attribute__((ext_vector_type(4))) float f32x4;
typedef __attribute__((ext_vector_type(16))) float f32x16;
typedef __attribute__((ext_vector_type(8))) __bf16 bf16x8;
typedef __attribute__((ext_vector_type(4))) __bf16 bf16x4;

union B8 {
    short8 s;
    bf16x8 b;
    unsigned short u[8];
};
union B4 {
    short4_ s;
    bf16x4 b;
    unsigned short u[4];
    int i[2];
};

static __device__ __forceinline__ unsigned short f2bf_rne(float f) {
    union { float f; unsigned u; } v; v.f = f;
    unsigned r = v.u + 0x7FFFu + ((v.u >> 16) & 1u);
    return (unsigned short)(r >> 16);
}

// ---------------------------------------------------------------------------
// GEMM body (unchanged from round 1)
// ---------------------------------------------------------------------------
template <bool A_F32, bool OUT_F32>
__device__ __forceinline__ void gemm_body(const void* __restrict__ Av,
                                          const float* __restrict__ B,
                                          const float* __restrict__ bias,
                                          void* __restrict__ Cv,
                                          int bpitch, int col0) {
    constexpr int PAD = 40;
    __shared__ unsigned short sA[64 * PAD];
    __shared__ unsigned short sBt[64 * PAD];

    const int t = threadIdx.x;
    const int wave = t >> 6;
    const int lane = t & 63;
    const int quad = lane >> 4;
    const int l15 = lane & 15;
    const int row0 = blockIdx.y * 64;

    f32x4 acc[4] = {};

    const int a_row = t >> 2;
    const int a_seg = t & 3;
    const int b_row = t >> 3;
    const int b_seg = t & 7;

    for (int k0 = 0; k0 < 1024; k0 += 32) {
        if constexpr (A_F32) {
            const float* A = (const float*)Av;
            const float* src = &A[(size_t)(row0 + a_row) * 1024 + k0 + a_seg * 8];
            f32x4 v0 = *(const f32x4*)src;
            f32x4 v1 = *(const f32x4*)(src + 4);
            B8 w;
#pragma unroll
            for (int j = 0; j < 4; ++j) {
                w.u[j] = f2bf_rne(v0[j]);
                w.u[4 + j] = f2bf_rne(v1[j]);
            }
            *(short8*)&sA[a_row * PAD + a_seg * 8] = w.s;
        } else {
            const unsigned short* A = (const unsigned short*)Av;
            short8 vv = *(const short8*)&A[(size_t)(row0 + a_row) * 1024 + k0 + a_seg * 8];
            *(short8*)&sA[a_row * PAD + a_seg * 8] = vv;
        }
        {
            const float* src = &B[(size_t)(k0 + b_row) * bpitch + b_seg * 8];
            f32x4 v0 = *(const f32x4*)src;
            f32x4 v1 = *(const f32x4*)(src + 4);
#pragma unroll
            for (int j = 0; j < 4; ++j) {
                sBt[(b_seg * 8 + j) * PAD + b_row] = f2bf_rne(v0[j]);
                sBt[(b_seg * 8 + 4 + j) * PAD + b_row] = f2bf_rne(v1[j]);
            }
        }
        __syncthreads();
        B8 af;
        af.s = *(const short8*)&sA[(wave * 16 + l15) * PAD + quad * 8];
#pragma unroll
        for (int j = 0; j < 4; ++j) {
            B8 bf;
            bf.s = *(const short8*)&sBt[(j * 16 + l15) * PAD + quad * 8];
            acc[j] = __builtin_amdgcn_mfma_f32_16x16x32_bf16(af.b, bf.b, acc[j], 0, 0, 0);
        }
        __syncthreads();
    }
#pragma unroll
    for (int j = 0; j < 4; ++j) {
        int cl = j * 16 + l15;
        float bb = bias[cl];
#pragma unroll
        for (int r = 0; r < 4; ++r) {
            int grow = row0 + wave * 16 + quad * 4 + r;
            size_t idx = (size_t)grow * 1024 + col0 + cl;
            float val = acc[j][r] + bb;
            if constexpr (OUT_F32)
                ((float*)Cv)[idx] = val;
            else
                ((unsigned short*)Cv)[idx] = f2bf_rne(val);
        }
    }
}

__global__ __launch_bounds__(256) void qkv_proj(
    const float* __restrict__ Q, const float* __restrict__ Kx, const float* __restrict__ Vx,
    const float* __restrict__ Wq, const float* __restrict__ Wk, const float* __restrict__ Wv,
    const float* __restrict__ bq, const float* __restrict__ bk, const float* __restrict__ bv,
    unsigned short* q_o, unsigned short* k_o, unsigned short* v_o) {
    const int h = blockIdx.x;
    const int p = blockIdx.z;
    const float* A = (p == 0) ? Q : (p == 1 ? Kx : Vx);
    const float* W = ((p == 0) ? Wq : (p == 1 ? Wk : Wv)) + (size_t)h * 1024 * 64;
    const float* bias = ((p == 0) ? bq : (p == 1 ? bk : bv)) + h * 64;
    unsigned short* C = (p == 0) ? q_o : (p == 1 ? k_o : v_o);
    gemm_body<true, false>(A, W, bias, C, 64, h * 64);
}

__global__ __launch_bounds__(256) void out_proj(const unsigned short* __restrict__ A,
                                                const float* __restrict__ Wo,
                                                const float* __restrict__ bo,
                                                float* __restrict__ C) {
    const int ct = blockIdx.x;
    gemm_body<false, true>(A, Wo + ct * 64, bo + ct * 64, C, 1024, ct * 64);
}

// ---------------------------------------------------------------------------
// Flash-style attention.
// Grid (8 q-tiles, 4 b, 16 h); 256 threads. Block: 128 q-rows, wave w: 32 q.
// K-loop: 16 tiles of 64 sk. LDS: sK[64][72] bf16, sVt[64][72] bf16 (transposed),
// sBits[16] u64 (mask bits). No online max (bounded scores, shift-invariant).
// ---------------------------------------------------------------------------
#define KP 72
#define VP 72
#define SCALE_L2E 0.18033688011112042f  // (1/8) * log2(e)

#if __has_builtin(__builtin_amdgcn_mfma_f32_32x32x8bf16_1k)
#define HAVE_X8 1
#endif

__global__ __launch_bounds__(256) void attn_kernel(
    const unsigned short* __restrict__ q,
    const unsigned short* __restrict__ k,
    const unsigned short* __restrict__ v,
    const int* __restrict__ key_mask,
    unsigned short* __restrict__ o) {
    __shared__ unsigned short sK[64 * KP];
    __shared__ unsigned short sVt[64 * VP];
    __shared__ unsigned long long sBits[16];

    const int t = threadIdx.x;
    const int wave = t >> 6;
    const int lane = t & 63;
    const int n31 = lane & 31;
    const int hh = lane >> 5;  // half-wave 0/1
    const int b = blockIdx.y;
    const int h = blockIdx.z;
    const int q0w = blockIdx.x * 128 + wave * 32;

    // Build 1024-bit key mask (bit set => masked out) via ballot.
#pragma unroll
    for (int i = 0; i < 4; ++i) {
        const int idx = i * 4 + wave;
        const int sk = idx * 64 + lane;
        unsigned long long bal = __ballot(key_mask[sk * 4 + b] != 0);
        if (lane == 0) sBits[idx] = bal;
    }

    // Q fragments in registers: B-frag of 32x32x16 => B[n=lane&31][k=hh*8+j]
    bf16x8 qf[4];
    {
        const unsigned short* qrow =
            q + ((size_t)(q0w + n31) * 4 + b) * 1024 + h * 64 + hh * 8;
#pragma unroll
        for (int kc = 0; kc < 4; ++kc) {
            B8 tmp;
            tmp.s = *(const short8*)(qrow + kc * 16);
            qf[kc] = tmp.b;
        }
    }

    f32x16 O0 = {}, O1 = {};
    float lacc = 0.f;

    const unsigned short* kbase = k + (size_t)b * 1024 + h * 64;
    const unsigned short* vbase = v + (size_t)b * 1024 + h * 64;
    const int srow = t >> 3;  // 0..31
    const int sseg = t & 7;   // 0..7

    for (int kt = 0; kt < 16; ++kt) {
        __syncthreads();  // prev iter's PV reads done before restage
        const int k0 = kt * 64;
        // --- stage K tile [64 sk][64 k] and V^T tile [64 dh][64 sk] ---
#pragma unroll
        for (int p = 0; p < 2; ++p) {
            const int row = p * 32 + srow;
            const short8 kv =
                *(const short8*)(kbase + (size_t)(k0 + row) * 4096 + sseg * 8);
            *(short8*)&sK[row * KP + sseg * 8] = kv;
            B8 vv;
            vv.s = *(const short8*)(vbase + (size_t)(k0 + row) * 4096 + sseg * 8);
#pragma unroll
            for (int s = 0; s < 8; ++s) {
                const int j = (s + row + sseg) & 7;  // stagger to spread banks
                sVt[(sseg * 8 + j) * VP + row] = vv.u[j];
            }
        }
        __syncthreads();

        const unsigned long long word = sBits[kt];
        B4 pfr[2][4];
#pragma unroll
        for (int blk = 0; blk < 2; ++blk) {
            const int skb = blk * 32;
            // S^T[sk=32][q=32] : A = K rows, B = Q rows
            f32x16 c = {};
#pragma unroll
            for (int kc = 0; kc < 4; ++kc) {
                B8 af;
                af.s = *(const short8*)&sK[(skb + n31) * KP + kc * 16 + hh * 8];
                c = __builtin_amdgcn_mfma_f32_32x32x16_bf16(af.b, qf[kc], c, 0, 0, 0);
            }
            // p = exp2(s*scale'); masked -> 0; accumulate row sum; pack bf16
#pragma unroll
            for (int g = 0; g < 4; ++g) {
                const int shift = skb + g * 8 + hh * 4;
                const unsigned nib = (unsigned)(word >> shift) & 0xFu;
#pragma unroll
                for (int j = 0; j < 4; ++j) {
                    float pv = exp2f(c[g * 4 + j] * SCALE_L2E);
                    pv = (nib & (1u << j)) ? 0.f : pv;
                    lacc += pv;
                    pfr[blk][g].u[j] = f2bf_rne(pv);
                }
            }
        }
        // --- O += P·V ---
#if HAVE_X8
#pragma unroll
        for (int blk = 0; blk < 2; ++blk) {
#pragma unroll
            for (int g = 0; g < 4; ++g) {
                const int sko = blk * 32 + g * 8 + hh * 4;
                B4 b0, b1;
                b0.s = *(const short4_*)&sVt[n31 * VP + sko];
                b1.s = *(const short4_*)&sVt[(32 + n31) * VP + sko];
                O0 = __builtin_amdgcn_mfma_f32_32x32x8bf16_1k(pfr[blk][g].s, b0.s, O0, 0, 0, 0);
                O1 = __builtin_amdgcn_mfma_f32_32x32x8bf16_1k(pfr[blk][g].s, b1.s, O1, 0, 0, 0);
            }
        }
#else
        // Fallback: exchange half-wave P groups, use 32x32x16.
#pragma unroll
        for (int blk = 0; blk < 2; ++blk) {
            B4 par[4];
#pragma unroll
            for (int g = 0; g < 4; ++g) {
                par[g].i[0] = __shfl_xor(pfr[blk][g].i[0], 32);
                par[g].i[1] = __shfl_xor(pfr[blk][g].i[1], 32);
            }
#pragma unroll
            for (int w = 0; w < 2; ++w) {
                const int gsel = 2 * w + hh;
                B4 lo = (hh == 0) ? pfr[blk][gsel] : par[gsel];
                B4 hi = (hh == 0) ? par[gsel] : pfr[blk][gsel];
                B8 afr;
#pragma unroll
                for (int j = 0; j < 4; ++j) {
                    afr.u[j] = lo.u[j];
                    afr.u[4 + j] = hi.u[j];
                }
                const int sko = blk * 32 + w * 16 + hh * 8;
                B8 b0, b1;
                b0.s = *(const short8*)&sVt[n31 * VP + sko];
                b1.s = *(const short8*)&sVt[(32 + n31) * VP + sko];
                O0 = __builtin_amdgcn_mfma_f32_32x32x16_bf16(afr.b, b0.b, O0, 0, 0, 0);
                O1 = __builtin_amdgcn_mfma_f32_32x32x16_bf16(afr.b, b1.b, O1, 0, 0, 0);
            }
        }
#endif
    }

    // --- epilogue: O[q][dh] rows q=(r&3)+8*(r>>2)+4*hh, cols dh=dt*32+n31 ---
    const float lred = lacc + __shfl_xor(lacc, 32);
    unsigned short* obase = o + ((size_t)q0w * 4 + b) * 1024 + h * 64 + n31;
#pragma unroll
    for (int r = 0; r < 16; ++r) {
        const int qr = (r & 3) + 8 * (r >> 2) + 4 * hh;
        const float lq = __shfl(lred, qr);
        const float inv = 1.0f / lq;
        obase[(size_t)qr * 4096] = f2bf_rne(O0[r] * inv);
        obase[(size_t)qr * 4096 + 32] = f2bf_rne(O1[r] * inv);
    }
}

extern "C" void kernel_launch(void* const* d_in, const int* in_sizes, int n_in,
                              void* d_out, int out_size, void* d_ws, size_t ws_size,
                              hipStream_t stream) {
    const float* query = (const float*)d_in[0];
    const float* key_ = (const float*)d_in[1];
    const float* value = (const float*)d_in[2];
    const int* key_mask = (const int*)d_in[3];
    const float* Wq = (const float*)d_in[4];
    const float* bq = (const float*)d_in[5];
    const float* Wk = (const float*)d_in[6];
    const float* bk = (const float*)d_in[7];
    const float* Wv = (const float*)d_in[8];
    const float* bv = (const float*)d_in[9];
    const float* Wo = (const float*)d_in[10];
    const float* bo = (const float*)d_in[11];
    float* out = (float*)d_out;

    const size_t NE = (size_t)4096 * 1024;
    unsigned short* q_ws = (unsigned short*)d_ws;
    unsigned short* k_ws = q_ws + NE;
    unsigned short* v_ws = k_ws + NE;
    unsigned short* a_ws = v_ws + NE;

    qkv_proj<<<dim3(16, 64, 3), 256, 0, stream>>>(query, key_, value, Wq, Wk, Wv,
                                                  bq, bk, bv, q_ws, k_ws, v_ws);
    attn_kernel<<<dim3(8, 4, 16), 256, 0, stream>>>(q_ws, k_ws, v_ws, key_mask, a_ws);
    out_proj<<<dim3(16, 64, 1), 256, 0, stream>>>(a_ws, Wo, bo, out);
}

// Round 3
// 296.511 us; speedup vs baseline: 2.2186x; 1.2774x over previous
//
#include <hip/hip_runtime.h>
#include <hip/hip_bf16.h>

// MultiHeadAttention S=1024 B=4 D=1024 H=16 DH=64
// [0] transpose_w: Wq/Wk/Wv/Wo f32 -> bf16 B^T[n][k] (one-time, ~17MB)
// [1] qkv_gemm: M=4096 x N=1024(heads concat) x K=1024, 3 proj in grid.z,
//     128x128 tile BK=64, A f32->bf16 convert staging, B via global_load_lds.
// [2] attn: flash-style (unchanged from round 2)
// [3] out_gemm: same body, A=attn_out bf16 (global_load_lds), B^T=WoT, f32 out.
// ws (bf16 elems): q @0, k @NE, v @2NE, attn_out @3NE, WT(4x1M) @4NE  (40MB)

typedef __attribute__((ext_vector_type(8))) short short8;
typedef __attribute__((ext_vector_type(4))) short short4_;
typedef __attribute__((ext_vector_type(4))) float f32x4;
typedef __attribute__((ext_vector_type(16))) float f32x16;
typedef __attribute__((ext_vector_type(8))) __bf16 bf16x8;
typedef __attribute__((ext_vector_type(4))) __bf16 bf16x4;

union B8 {
    short8 s;
    bf16x8 b;
    unsigned short u[8];
};
union B4 {
    short4_ s;
    bf16x4 b;
    unsigned short u[4];
    int i[2];
};

static __device__ __forceinline__ unsigned short f2bf_rne(float f) {
    union { float f; unsigned u; } v; v.f = f;
    unsigned r = v.u + 0x7FFFu + ((v.u >> 16) & 1u);
    return (unsigned short)(r >> 16);
}

// async global->LDS, 16B per lane; LDS dest = wave-uniform base + lane*16.
static __device__ __forceinline__ void async_lds16(const void* g, const void* l) {
    __builtin_amdgcn_global_load_lds(
        (const __attribute__((address_space(1))) unsigned int*)(unsigned long long)g,
        (__attribute__((address_space(3))) unsigned int*)(unsigned int)(unsigned long long)l,
        16, 0, 0);
}

// ---------------------------------------------------------------------------
// One-time weight transpose+convert: dst[n][k] = bf16(src[k][n]), 64x64 tiles.
// z<3: per-head W[h] is [1024 k][64 n] pitch 64; z==3: Wo [1024 k][1024 n].
// ---------------------------------------------------------------------------
__global__ __launch_bounds__(256) void transpose_w(
    const float* __restrict__ Wq, const float* __restrict__ Wk,
    const float* __restrict__ Wv, const float* __restrict__ Wo,
    unsigned short* __restrict__ WT) {
    __shared__ float sT[64][65];
    const int t = threadIdx.x;
    const int dtile = blockIdx.x;  // source-row (k) tile
    const int sub = blockIdx.y;    // head (z<3) or n-tile (z==3)
    const int z = blockIdx.z;

    const float* src;
    int spitch;
    unsigned short* dst;
    if (z < 3) {
        const float* W = (z == 0) ? Wq : (z == 1) ? Wk : Wv;
        src = W + (size_t)sub * 65536 + (size_t)dtile * 64 * 64;
        spitch = 64;
        dst = WT + (size_t)z * 1048576 + (size_t)(sub * 64) * 1024 + dtile * 64;
    } else {
        src = Wo + (size_t)dtile * 64 * 1024 + sub * 64;
        spitch = 1024;
        dst = WT + (size_t)3 * 1048576 + (size_t)(sub * 64) * 1024 + dtile * 64;
    }

    const int r = t >> 2;
    const int cseg = (t & 3) * 16;
#pragma unroll
    for (int i = 0; i < 4; ++i) {
        f32x4 v = *(const f32x4*)(src + (size_t)r * spitch + cseg + i * 4);
#pragma unroll
        for (int j = 0; j < 4; ++j) sT[r][cseg + i * 4 + j] = v[j];
    }
    __syncthreads();
    // write: dst row n = r, cols k = cseg..cseg+15  (dst[n][k] = sT[k][n])
    B8 w0, w1;
#pragma unroll
    for (int i = 0; i < 8; ++i) {
        w0.u[i] = f2bf_rne(sT[cseg + i][r]);
        w1.u[i] = f2bf_rne(sT[cseg + 8 + i][r]);
    }
    *(short8*)(dst + (size_t)r * 1024 + cseg) = w0.s;
    *(short8*)(dst + (size_t)r * 1024 + cseg + 8) = w1.s;
}

// ---------------------------------------------------------------------------
// 128x128-tile GEMM (BK=64): C[4096,1024] = A[4096,1024] * B^T[1024,1024] + bias
// 4 waves in 2x2; wave = 64x64 C quadrant = 4x4 frags of 16x16x32.
// ---------------------------------------------------------------------------
template <bool A_F32, bool OUT_F32>
__device__ __forceinline__ void gemm128(const void* __restrict__ Av,
                                        const unsigned short* __restrict__ Bt,
                                        const float* __restrict__ bias,
                                        void* __restrict__ Cv) {
    __shared__ unsigned short sA[128 * 64];
    __shared__ unsigned short sB[128 * 64];
    const int t = threadIdx.x;
    const int w = t >> 6;
    const int lane = t & 63;
    const int quad = lane >> 4;
    const int l15 = lane & 15;
    const int wr = w >> 1;
    const int wc = w & 1;
    const int row0 = blockIdx.y * 128;
    const int col0 = blockIdx.x * 128;
    const int lrow8 = lane >> 3;  // 0..7
    const int lseg = lane & 7;    // 0..7

    f32x4 acc[4][4] = {};

    for (int k0 = 0; k0 < 1024; k0 += 64) {
        // --- stage B^T tile: wave w rows [w*32, w*32+32), 4 issues x 8 rows ---
#pragma unroll
        for (int i = 0; i < 4; ++i) {
            const int rr = w * 32 + i * 8;  // wave-uniform
            async_lds16(Bt + (size_t)(col0 + rr + lrow8) * 1024 + k0 + lseg * 8,
                        &sB[rr * 64]);
        }
        // --- stage A tile ---
        if constexpr (A_F32) {
            const float* A = (const float*)Av;
#pragma unroll
            for (int i = 0; i < 4; ++i) {
                const int rr = w * 32 + i * 8 + lrow8;
                const float* src = A + (size_t)(row0 + rr) * 1024 + k0 + lseg * 8;
                f32x4 v0 = *(const f32x4*)src;
                f32x4 v1 = *(const f32x4*)(src + 4);
                B8 pk;
#pragma unroll
                for (int j = 0; j < 4; ++j) {
                    pk.u[j] = f2bf_rne(v0[j]);
                    pk.u[4 + j] = f2bf_rne(v1[j]);
                }
                *(short8*)&sA[rr * 64 + lseg * 8] = pk.s;
            }
        } else {
            const unsigned short* A = (const unsigned short*)Av;
#pragma unroll
            for (int i = 0; i < 4; ++i) {
                const int rr = w * 32 + i * 8;
                async_lds16(A + (size_t)(row0 + rr + lrow8) * 1024 + k0 + lseg * 8,
                            &sA[rr * 64]);
            }
        }
        __syncthreads();
        // --- compute ---
#pragma unroll
        for (int kf = 0; kf < 2; ++kf) {
            B8 af[4], bf[4];
#pragma unroll
            for (int i = 0; i < 4; ++i)
                af[i].s = *(const short8*)&sA[(wr * 64 + i * 16 + l15) * 64 + kf * 32 + quad * 8];
#pragma unroll
            for (int j = 0; j < 4; ++j)
                bf[j].s = *(const short8*)&sB[(wc * 64 + j * 16 + l15) * 64 + kf * 32 + quad * 8];
#pragma unroll
            for (int i = 0; i < 4; ++i)
#pragma unroll
                for (int j = 0; j < 4; ++j)
                    acc[i][j] = __builtin_amdgcn_mfma_f32_16x16x32_bf16(af[i].b, bf[j].b,
                                                                        acc[i][j], 0, 0, 0);
        }
        __syncthreads();
    }
    // --- epilogue ---
#pragma unroll
    for (int j = 0; j < 4; ++j) {
        const int col = col0 + wc * 64 + j * 16 + l15;
        const float bb = bias[col];
#pragma unroll
        for (int i = 0; i < 4; ++i) {
#pragma unroll
            for (int r = 0; r < 4; ++r) {
                const int row = row0 + wr * 64 + i * 16 + quad * 4 + r;
                const size_t idx = (size_t)row * 1024 + col;
                const float val = acc[i][j][r] + bb;
                if constexpr (OUT_F32)
                    ((float*)Cv)[idx] = val;
                else
                    ((unsigned short*)Cv)[idx] = f2bf_rne(val);
            }
        }
    }
}

__global__ __launch_bounds__(256) void qkv_gemm(
    const float* __restrict__ Q, const float* __restrict__ Kx, const float* __restrict__ Vx,
    const unsigned short* __restrict__ WT,
    const float* __restrict__ bq, const float* __restrict__ bk, const float* __restrict__ bv,
    unsigned short* q_o, unsigned short* k_o, unsigned short* v_o) {
    const int p = blockIdx.z;
    const float* A = (p == 0) ? Q : (p == 1) ? Kx : Vx;
    const unsigned short* Bt = WT + (size_t)p * 1048576;
    const float* bias = (p == 0) ? bq : (p == 1) ? bk : bv;
    unsigned short* C = (p == 0) ? q_o : (p == 1) ? k_o : v_o;
    gemm128<true, false>(A, Bt, bias, C);
}

__global__ __launch_bounds__(256) void out_gemm(const unsigned short* __restrict__ A,
                                                const unsigned short* __restrict__ WT,
                                                const float* __restrict__ bo,
                                                float* __restrict__ C) {
    gemm128<false, true>(A, WT + (size_t)3 * 1048576, bo, C);
}

// ---------------------------------------------------------------------------
// Flash-style attention (unchanged from round 2).
// ---------------------------------------------------------------------------
#define KP 72
#define VP 72
#define SCALE_L2E 0.18033688011112042f  // (1/8) * log2(e)

#if __has_builtin(__builtin_amdgcn_mfma_f32_32x32x8bf16_1k)
#define HAVE_X8 1
#endif

__global__ __launch_bounds__(256) void attn_kernel(
    const unsigned short* __restrict__ q,
    const unsigned short* __restrict__ k,
    const unsigned short* __restrict__ v,
    const int* __restrict__ key_mask,
    unsigned short* __restrict__ o) {
    __shared__ unsigned short sK[64 * KP];
    __shared__ unsigned short sVt[64 * VP];
    __shared__ unsigned long long sBits[16];

    const int t = threadIdx.x;
    const int wave = t >> 6;
    const int lane = t & 63;
    const int n31 = lane & 31;
    const int hh = lane >> 5;
    const int b = blockIdx.y;
    const int h = blockIdx.z;
    const int q0w = blockIdx.x * 128 + wave * 32;

#pragma unroll
    for (int i = 0; i < 4; ++i) {
        const int idx = i * 4 + wave;
        const int sk = idx * 64 + lane;
        unsigned long long bal = __ballot(key_mask[sk * 4 + b] != 0);
        if (lane == 0) sBits[idx] = bal;
    }

    bf16x8 qf[4];
    {
        const unsigned short* qrow =
            q + ((size_t)(q0w + n31) * 4 + b) * 1024 + h * 64 + hh * 8;
#pragma unroll
        for (int kc = 0; kc < 4; ++kc) {
            B8 tmp;
            tmp.s = *(const short8*)(qrow + kc * 16);
            qf[kc] = tmp.b;
        }
    }

    f32x16 O0 = {}, O1 = {};
    float lacc = 0.f;

    const unsigned short* kbase = k + (size_t)b * 1024 + h * 64;
    const unsigned short* vbase = v + (size_t)b * 1024 + h * 64;
    const int srow = t >> 3;
    const int sseg = t & 7;

    for (int kt = 0; kt < 16; ++kt) {
        __syncthreads();
        const int k0 = kt * 64;
#pragma unroll
        for (int p = 0; p < 2; ++p) {
            const int row = p * 32 + srow;
            const short8 kv =
                *(const short8*)(kbase + (size_t)(k0 + row) * 4096 + sseg * 8);
            *(short8*)&sK[row * KP + sseg * 8] = kv;
            B8 vv;
            vv.s = *(const short8*)(vbase + (size_t)(k0 + row) * 4096 + sseg * 8);
#pragma unroll
            for (int s = 0; s < 8; ++s) {
                const int j = (s + row + sseg) & 7;
                sVt[(sseg * 8 + j) * VP + row] = vv.u[j];
            }
        }
        __syncthreads();

        const unsigned long long word = sBits[kt];
        B4 pfr[2][4];
#pragma unroll
        for (int blk = 0; blk < 2; ++blk) {
            const int skb = blk * 32;
            f32x16 c = {};
#pragma unroll
            for (int kc = 0; kc < 4; ++kc) {
                B8 af;
                af.s = *(const short8*)&sK[(skb + n31) * KP + kc * 16 + hh * 8];
                c = __builtin_amdgcn_mfma_f32_32x32x16_bf16(af.b, qf[kc], c, 0, 0, 0);
            }
#pragma unroll
            for (int g = 0; g < 4; ++g) {
                const int shift = skb + g * 8 + hh * 4;
                const unsigned nib = (unsigned)(word >> shift) & 0xFu;
#pragma unroll
                for (int j = 0; j < 4; ++j) {
                    float pv = exp2f(c[g * 4 + j] * SCALE_L2E);
                    pv = (nib & (1u << j)) ? 0.f : pv;
                    lacc += pv;
                    pfr[blk][g].u[j] = f2bf_rne(pv);
                }
            }
        }
#if HAVE_X8
#pragma unroll
        for (int blk = 0; blk < 2; ++blk) {
#pragma unroll
            for (int g = 0; g < 4; ++g) {
                const int sko = blk * 32 + g * 8 + hh * 4;
                B4 b0, b1;
                b0.s = *(const short4_*)&sVt[n31 * VP + sko];
                b1.s = *(const short4_*)&sVt[(32 + n31) * VP + sko];
                O0 = __builtin_amdgcn_mfma_f32_32x32x8bf16_1k(pfr[blk][g].s, b0.s, O0, 0, 0, 0);
                O1 = __builtin_amdgcn_mfma_f32_32x32x8bf16_1k(pfr[blk][g].s, b1.s, O1, 0, 0, 0);
            }
        }
#else
#pragma unroll
        for (int blk = 0; blk < 2; ++blk) {
            B4 par[4];
#pragma unroll
            for (int g = 0; g < 4; ++g) {
                par[g].i[0] = __shfl_xor(pfr[blk][g].i[0], 32);
                par[g].i[1] = __shfl_xor(pfr[blk][g].i[1], 32);
            }
#pragma unroll
            for (int w = 0; w < 2; ++w) {
                const int gsel = 2 * w + hh;
                B4 lo = (hh == 0) ? pfr[blk][gsel] : par[gsel];
                B4 hi = (hh == 0) ? par[gsel] : pfr[blk][gsel];
                B8 afr;
#pragma unroll
                for (int j = 0; j < 4; ++j) {
                    afr.u[j] = lo.u[j];
                    afr.u[4 + j] = hi.u[j];
                }
                const int sko = blk * 32 + w * 16 + hh * 8;
                B8 b0, b1;
                b0.s = *(const short8*)&sVt[n31 * VP + sko];
                b1.s = *(const short8*)&sVt[(32 + n31) * VP + sko];
                O0 = __builtin_amdgcn_mfma_f32_32x32x16_bf16(afr.b, b0.b, O0, 0, 0, 0);
                O1 = __builtin_amdgcn_mfma_f32_32x32x16_bf16(afr.b, b1.b, O1, 0, 0, 0);
            }
        }
#endif
    }

    const float lred = lacc + __shfl_xor(lacc, 32);
    unsigned short* obase = o + ((size_t)q0w * 4 + b) * 1024 + h * 64 + n31;
#pragma unroll
    for (int r = 0; r < 16; ++r) {
        const int qr = (r & 3) + 8 * (r >> 2) + 4 * hh;
        const float lq = __shfl(lred, qr);
        const float inv = 1.0f / lq;
        obase[(size_t)qr * 4096] = f2bf_rne(O0[r] * inv);
        obase[(size_t)qr * 4096 + 32] = f2bf_rne(O1[r] * inv);
    }
}

extern "C" void kernel_launch(void* const* d_in, const int* in_sizes, int n_in,
                              void* d_out, int out_size, void* d_ws, size_t ws_size,
                              hipStream_t stream) {
    const float* query = (const float*)d_in[0];
    const float* key_ = (const float*)d_in[1];
    const float* value = (const float*)d_in[2];
    const int* key_mask = (const int*)d_in[3];
    const float* Wq = (const float*)d_in[4];
    const float* bq = (const float*)d_in[5];
    const float* Wk = (const float*)d_in[6];
    const float* bk = (const float*)d_in[7];
    const float* Wv = (const float*)d_in[8];
    const float* bv = (const float*)d_in[9];
    const float* Wo = (const float*)d_in[10];
    const float* bo = (const float*)d_in[11];
    float* out = (float*)d_out;

    const size_t NE = (size_t)4096 * 1024;
    unsigned short* q_ws = (unsigned short*)d_ws;
    unsigned short* k_ws = q_ws + NE;
    unsigned short* v_ws = k_ws + NE;
    unsigned short* a_ws = v_ws + NE;
    unsigned short* wt_ws = a_ws + NE;  // 4 x 1M bf16 (WqT,WkT,WvT,WoT)

    transpose_w<<<dim3(16, 16, 4), 256, 0, stream>>>(Wq, Wk, Wv, Wo, wt_ws);
    qkv_gemm<<<dim3(8, 32, 3), 256, 0, stream>>>(query, key_, value, wt_ws,
                                                 bq, bk, bv, q_ws, k_ws, v_ws);
    attn_kernel<<<dim3(8, 4, 16), 256, 0, stream>>>(q_ws, k_ws, v_ws, key_mask, a_ws);
    out_gemm<<<dim3(8, 32, 1), 256, 0, stream>>>(a_ws, wt_ws, bo, out);
}

// Round 4
// 256.478 us; speedup vs baseline: 2.5648x; 1.1561x over previous
//
#include <hip/hip_runtime.h>
#include <hip/hip_bf16.h>

// MultiHeadAttention S=1024 B=4 D=1024 H=16 DH=64
// [0] transpose_w: Wq/Wk/Wv/Wo f32 -> bf16 B^T[n][k] (one-time)
// [1] qkv_gemm: 128x128 tile GEMM; q output pre-scaled by log2(e)/8.
// [2] attn: flash-style, LDS double-buffered (1 sync/kt), mask via MFMA
//     accumulator-init bias table, l via ones-column MFMA.
// [3] out_gemm.
// ws (bf16 elems): q @0, k @NE, v @2NE, attn_out @3NE, WT(4x1M) @4NE (40MB)

typedef __attribute__((ext_vector_type(8))) short short8;
typedef __attribute__((ext_vector_type(4))) short short4_;
typedef __attribute__((ext_vector_type(4))) float f32x4;
typedef __attribute__((ext_vector_type(16))) float f32x16;
typedef __attribute__((ext_vector_type(8))) __bf16 bf16x8;
typedef __attribute__((ext_vector_type(4))) __bf16 bf16x4;

union B8 {
    short8 s;
    bf16x8 b;
    unsigned short u[8];
};
union B4 {
    short4_ s;
    bf16x4 b;
    unsigned short u[4];
    int i[2];
};

#if __has_builtin(__builtin_amdgcn_exp2f)
#define EXP2(x) __builtin_amdgcn_exp2f(x)
#else
#define EXP2(x) exp2f(x)
#endif
#if __has_builtin(__builtin_amdgcn_rcpf)
#define RCP(x) __builtin_amdgcn_rcpf(x)
#else
#define RCP(x) (1.0f / (x))
#endif

static __device__ __forceinline__ unsigned short f2bf_rne(float f) {
    union { float f; unsigned u; } v; v.f = f;
    unsigned r = v.u + 0x7FFFu + ((v.u >> 16) & 1u);
    return (unsigned short)(r >> 16);
}

static __device__ __forceinline__ void async_lds16(const void* g, const void* l) {
    __builtin_amdgcn_global_load_lds(
        (const __attribute__((address_space(1))) unsigned int*)(unsigned long long)g,
        (__attribute__((address_space(3))) unsigned int*)(unsigned int)(unsigned long long)l,
        16, 0, 0);
}

// ---------------------------------------------------------------------------
// One-time weight transpose+convert: dst[n][k] = bf16(src[k][n]).
// ---------------------------------------------------------------------------
__global__ __launch_bounds__(256) void transpose_w(
    const float* __restrict__ Wq, const float* __restrict__ Wk,
    const float* __restrict__ Wv, const float* __restrict__ Wo,
    unsigned short* __restrict__ WT) {
    __shared__ float sT[64][65];
    const int t = threadIdx.x;
    const int dtile = blockIdx.x;
    const int sub = blockIdx.y;
    const int z = blockIdx.z;

    const float* src;
    int spitch;
    unsigned short* dst;
    if (z < 3) {
        const float* W = (z == 0) ? Wq : (z == 1) ? Wk : Wv;
        src = W + (size_t)sub * 65536 + (size_t)dtile * 64 * 64;
        spitch = 64;
        dst = WT + (size_t)z * 1048576 + (size_t)(sub * 64) * 1024 + dtile * 64;
    } else {
        src = Wo + (size_t)dtile * 64 * 1024 + sub * 64;
        spitch = 1024;
        dst = WT + (size_t)3 * 1048576 + (size_t)(sub * 64) * 1024 + dtile * 64;
    }

    const int r = t >> 2;
    const int cseg = (t & 3) * 16;
#pragma unroll
    for (int i = 0; i < 4; ++i) {
        f32x4 v = *(const f32x4*)(src + (size_t)r * spitch + cseg + i * 4);
#pragma unroll
        for (int j = 0; j < 4; ++j) sT[r][cseg + i * 4 + j] = v[j];
    }
    __syncthreads();
    B8 w0, w1;
#pragma unroll
    for (int i = 0; i < 8; ++i) {
        w0.u[i] = f2bf_rne(sT[cseg + i][r]);
        w1.u[i] = f2bf_rne(sT[cseg + 8 + i][r]);
    }
    *(short8*)(dst + (size_t)r * 1024 + cseg) = w0.s;
    *(short8*)(dst + (size_t)r * 1024 + cseg + 8) = w1.s;
}

// ---------------------------------------------------------------------------
// 128x128-tile GEMM (BK=64) with output scale.
// ---------------------------------------------------------------------------
template <bool A_F32, bool OUT_F32>
__device__ __forceinline__ void gemm128(const void* __restrict__ Av,
                                        const unsigned short* __restrict__ Bt,
                                        const float* __restrict__ bias,
                                        void* __restrict__ Cv, float oscale) {
    __shared__ unsigned short sA[128 * 64];
    __shared__ unsigned short sB[128 * 64];
    const int t = threadIdx.x;
    const int w = t >> 6;
    const int lane = t & 63;
    const int quad = lane >> 4;
    const int l15 = lane & 15;
    const int wr = w >> 1;
    const int wc = w & 1;
    const int row0 = blockIdx.y * 128;
    const int col0 = blockIdx.x * 128;
    const int lrow8 = lane >> 3;
    const int lseg = lane & 7;

    f32x4 acc[4][4] = {};

    for (int k0 = 0; k0 < 1024; k0 += 64) {
#pragma unroll
        for (int i = 0; i < 4; ++i) {
            const int rr = w * 32 + i * 8;
            async_lds16(Bt + (size_t)(col0 + rr + lrow8) * 1024 + k0 + lseg * 8,
                        &sB[rr * 64]);
        }
        if constexpr (A_F32) {
            const float* A = (const float*)Av;
#pragma unroll
            for (int i = 0; i < 4; ++i) {
                const int rr = w * 32 + i * 8 + lrow8;
                const float* src = A + (size_t)(row0 + rr) * 1024 + k0 + lseg * 8;
                f32x4 v0 = *(const f32x4*)src;
                f32x4 v1 = *(const f32x4*)(src + 4);
                B8 pk;
#pragma unroll
                for (int j = 0; j < 4; ++j) {
                    pk.u[j] = f2bf_rne(v0[j]);
                    pk.u[4 + j] = f2bf_rne(v1[j]);
                }
                *(short8*)&sA[rr * 64 + lseg * 8] = pk.s;
            }
        } else {
            const unsigned short* A = (const unsigned short*)Av;
#pragma unroll
            for (int i = 0; i < 4; ++i) {
                const int rr = w * 32 + i * 8;
                async_lds16(A + (size_t)(row0 + rr + lrow8) * 1024 + k0 + lseg * 8,
                            &sA[rr * 64]);
            }
        }
        __syncthreads();
#pragma unroll
        for (int kf = 0; kf < 2; ++kf) {
            B8 af[4], bf[4];
#pragma unroll
            for (int i = 0; i < 4; ++i)
                af[i].s = *(const short8*)&sA[(wr * 64 + i * 16 + l15) * 64 + kf * 32 + quad * 8];
#pragma unroll
            for (int j = 0; j < 4; ++j)
                bf[j].s = *(const short8*)&sB[(wc * 64 + j * 16 + l15) * 64 + kf * 32 + quad * 8];
#pragma unroll
            for (int i = 0; i < 4; ++i)
#pragma unroll
                for (int j = 0; j < 4; ++j)
                    acc[i][j] = __builtin_amdgcn_mfma_f32_16x16x32_bf16(af[i].b, bf[j].b,
                                                                        acc[i][j], 0, 0, 0);
        }
        __syncthreads();
    }
#pragma unroll
    for (int j = 0; j < 4; ++j) {
        const int col = col0 + wc * 64 + j * 16 + l15;
        const float bb = bias[col];
#pragma unroll
        for (int i = 0; i < 4; ++i) {
#pragma unroll
            for (int r = 0; r < 4; ++r) {
                const int row = row0 + wr * 64 + i * 16 + quad * 4 + r;
                const size_t idx = (size_t)row * 1024 + col;
                const float val = (acc[i][j][r] + bb) * oscale;
                if constexpr (OUT_F32)
                    ((float*)Cv)[idx] = val;
                else
                    ((unsigned short*)Cv)[idx] = f2bf_rne(val);
            }
        }
    }
}

#define SCALE_L2E 0.18033688011112042f  // (1/8) * log2(e)

__global__ __launch_bounds__(256) void qkv_gemm(
    const float* __restrict__ Q, const float* __restrict__ Kx, const float* __restrict__ Vx,
    const unsigned short* __restrict__ WT,
    const float* __restrict__ bq, const float* __restrict__ bk, const float* __restrict__ bv,
    unsigned short* q_o, unsigned short* k_o, unsigned short* v_o) {
    const int p = blockIdx.z;
    const float* A = (p == 0) ? Q : (p == 1) ? Kx : Vx;
    const unsigned short* Bt = WT + (size_t)p * 1048576;
    const float* bias = (p == 0) ? bq : (p == 1) ? bk : bv;
    unsigned short* C = (p == 0) ? q_o : (p == 1) ? k_o : v_o;
    const float osc = (p == 0) ? SCALE_L2E : 1.0f;  // pre-scale q for attn exp2
    gemm128<true, false>(A, Bt, bias, C, osc);
}

__global__ __launch_bounds__(256) void out_gemm(const unsigned short* __restrict__ A,
                                                const unsigned short* __restrict__ WT,
                                                const float* __restrict__ bo,
                                                float* __restrict__ C) {
    gemm128<false, true>(A, WT + (size_t)3 * 1048576, bo, C, 1.0f);
}

// ---------------------------------------------------------------------------
// Flash-style attention, double-buffered LDS, 1 sync per k-tile.
// ---------------------------------------------------------------------------
#define TP 72

#if __has_builtin(__builtin_amdgcn_mfma_f32_32x32x8bf16_1k)
#define HAVE_X8 1
#endif

__global__ __launch_bounds__(256) void attn_kernel(
    const unsigned short* __restrict__ q,   // pre-scaled by log2(e)/8
    const unsigned short* __restrict__ k,
    const unsigned short* __restrict__ v,
    const int* __restrict__ key_mask,
    unsigned short* __restrict__ o) {
    __shared__ unsigned short sK[2][64 * TP];
    __shared__ unsigned short sVt[2][64 * TP];
    __shared__ float sBias[2048];  // [kt][blk][hh][r]
    __shared__ unsigned long long sBits[16];

    const int t = threadIdx.x;
    const int wave = t >> 6;
    const int lane = t & 63;
    const int n31 = lane & 31;
    const int hh = lane >> 5;
    const int b = blockIdx.y;
    const int h = blockIdx.z;
    const int q0w = blockIdx.x * 128 + wave * 32;
    const int srow = t >> 3;  // 0..31
    const int sseg = t & 7;   // 0..7

    // mask bits: bit set => masked out
#pragma unroll
    for (int i = 0; i < 4; ++i) {
        const int idx = i * 4 + wave;
        const int sk = idx * 64 + lane;
        unsigned long long bal = __ballot(key_mask[sk * 4 + b] != 0);
        if (lane == 0) sBits[idx] = bal;
    }
    __syncthreads();
    // accumulator-init bias table: -16384 => exp2 underflow => exact 0
#pragma unroll
    for (int i = 0; i < 8; ++i) {
        const int idx = t * 8 + i;
        const int r = idx & 15;
        const int hb = (idx >> 4) & 1;
        const int blk = (idx >> 5) & 1;
        const int kt = idx >> 6;
        const int row = (r & 3) + 8 * (r >> 2) + 4 * hb + blk * 32;
        sBias[idx] = ((sBits[kt] >> row) & 1ull) ? -16384.0f : 0.0f;
    }

    // Q fragments (B-operand of 32x32x16): B[n=lane&31][k=hh*8+j]
    bf16x8 qf[4];
    {
        const unsigned short* qrow =
            q + ((size_t)(q0w + n31) * 4 + b) * 1024 + h * 64 + hh * 8;
#pragma unroll
        for (int kc = 0; kc < 4; ++kc) {
            B8 tmp;
            tmp.s = *(const short8*)(qrow + kc * 16);
            qf[kc] = tmp.b;
        }
    }

    f32x16 O0 = {}, O1 = {}, L = {};
    B4 ones;
#pragma unroll
    for (int j = 0; j < 4; ++j) ones.u[j] = 0x3F80;  // bf16 1.0
#if !defined(HAVE_X8)
    B8 ones8;
#pragma unroll
    for (int j = 0; j < 8; ++j) ones8.u[j] = 0x3F80;
#endif

    const unsigned short* kbase = k + (size_t)b * 1024 + h * 64;
    const unsigned short* vbase = v + (size_t)b * 1024 + h * 64;

    // prologue: stage tile 0 into buffer 0
    {
        const unsigned short* kr = kbase + (size_t)srow * 4096 + sseg * 8;
        short8 ka = *(const short8*)kr;
        short8 kb2 = *(const short8*)(kr + (size_t)32 * 4096);
        const unsigned short* vr = vbase + (size_t)srow * 4096 + sseg * 8;
        B8 va, vb2;
        va.s = *(const short8*)vr;
        vb2.s = *(const short8*)(vr + (size_t)32 * 4096);
        *(short8*)&sK[0][srow * TP + sseg * 8] = ka;
        *(short8*)&sK[0][(32 + srow) * TP + sseg * 8] = kb2;
#pragma unroll
        for (int s = 0; s < 8; ++s) {
            const int j = (s + srow + sseg) & 7;
            sVt[0][(sseg * 8 + j) * TP + srow] = va.u[j];
            sVt[0][(sseg * 8 + j) * TP + 32 + srow] = vb2.u[j];
        }
    }

#pragma unroll 2
    for (int kt = 0; kt < 16; ++kt) {
        const int cur = kt & 1;
        __syncthreads();
        // issue next tile's global loads (completion awaited at ds_write below)
        short8 nka, nkb;
        B8 nva, nvb;
        if (kt < 15) {
            const int k0n = (kt + 1) * 64;
            const unsigned short* kr = kbase + (size_t)(k0n + srow) * 4096 + sseg * 8;
            nka = *(const short8*)kr;
            nkb = *(const short8*)(kr + (size_t)32 * 4096);
            const unsigned short* vr = vbase + (size_t)(k0n + srow) * 4096 + sseg * 8;
            nva.s = *(const short8*)vr;
            nvb.s = *(const short8*)(vr + (size_t)32 * 4096);
        }
        // --- S^T = K·Q^T with mask-bias accumulator init; exp2; pack bf16 ---
        B4 pfr[2][4];
#pragma unroll
        for (int blk = 0; blk < 2; ++blk) {
            f32x16 c;
            const f32x4* bp = (const f32x4*)&sBias[((kt * 2 + blk) * 2 + hh) * 16];
#pragma unroll
            for (int i = 0; i < 4; ++i) {
                f32x4 x = bp[i];
#pragma unroll
                for (int j = 0; j < 4; ++j) c[i * 4 + j] = x[j];
            }
#pragma unroll
            for (int kc = 0; kc < 4; ++kc) {
                B8 af;
                af.s = *(const short8*)&sK[cur][(blk * 32 + n31) * TP + kc * 16 + hh * 8];
                c = __builtin_amdgcn_mfma_f32_32x32x16_bf16(af.b, qf[kc], c, 0, 0, 0);
            }
#pragma unroll
            for (int g = 0; g < 4; ++g)
#pragma unroll
                for (int j = 0; j < 4; ++j)
                    pfr[blk][g].b[j] = (__bf16)EXP2(c[g * 4 + j]);
        }
        // --- O += P·V, l += P·1 ---
#if defined(HAVE_X8)
#pragma unroll
        for (int blk = 0; blk < 2; ++blk) {
#pragma unroll
            for (int g = 0; g < 4; ++g) {
                const int sko = blk * 32 + g * 8 + hh * 4;
                B4 b0, b1;
                b0.s = *(const short4_*)&sVt[cur][n31 * TP + sko];
                b1.s = *(const short4_*)&sVt[cur][(32 + n31) * TP + sko];
                O0 = __builtin_amdgcn_mfma_f32_32x32x8bf16_1k(pfr[blk][g].s, b0.s, O0, 0, 0, 0);
                O1 = __builtin_amdgcn_mfma_f32_32x32x8bf16_1k(pfr[blk][g].s, b1.s, O1, 0, 0, 0);
                L = __builtin_amdgcn_mfma_f32_32x32x8bf16_1k(pfr[blk][g].s, ones.s, L, 0, 0, 0);
            }
        }
#else
#pragma unroll
        for (int blk = 0; blk < 2; ++blk) {
            B4 par[4];
#pragma unroll
            for (int g = 0; g < 4; ++g) {
                par[g].i[0] = __shfl_xor(pfr[blk][g].i[0], 32);
                par[g].i[1] = __shfl_xor(pfr[blk][g].i[1], 32);
            }
#pragma unroll
            for (int w = 0; w < 2; ++w) {
                const int gsel = 2 * w + hh;
                B4 lo = (hh == 0) ? pfr[blk][gsel] : par[gsel];
                B4 hi = (hh == 0) ? par[gsel] : pfr[blk][gsel];
                B8 afr;
#pragma unroll
                for (int j = 0; j < 4; ++j) {
                    afr.u[j] = lo.u[j];
                    afr.u[4 + j] = hi.u[j];
                }
                const int sko = blk * 32 + w * 16 + hh * 8;
                B8 b0, b1;
                b0.s = *(const short8*)&sVt[cur][n31 * TP + sko];
                b1.s = *(const short8*)&sVt[cur][(32 + n31) * TP + sko];
                O0 = __builtin_amdgcn_mfma_f32_32x32x16_bf16(afr.b, b0.b, O0, 0, 0, 0);
                O1 = __builtin_amdgcn_mfma_f32_32x32x16_bf16(afr.b, b1.b, O1, 0, 0, 0);
                L = __builtin_amdgcn_mfma_f32_32x32x16_bf16(afr.b, ones8.b, L, 0, 0, 0);
            }
        }
#endif
        // --- write next tile into the other buffer (vmcnt waited here) ---
        if (kt < 15) {
            const int nb = 1 - cur;
            *(short8*)&sK[nb][srow * TP + sseg * 8] = nka;
            *(short8*)&sK[nb][(32 + srow) * TP + sseg * 8] = nkb;
#pragma unroll
            for (int s = 0; s < 8; ++s) {
                const int j = (s + srow + sseg) & 7;
                sVt[nb][(sseg * 8 + j) * TP + srow] = nva.u[j];
                sVt[nb][(sseg * 8 + j) * TP + 32 + srow] = nvb.u[j];
            }
        }
    }

    // --- epilogue: rows q=(r&3)+8*(r>>2)+4*hh; l from ones-MFMA (per-lane) ---
    unsigned short* obase = o + ((size_t)q0w * 4 + b) * 1024 + h * 64 + n31;
#pragma unroll
    for (int r = 0; r < 16; ++r) {
        const int qr = (r & 3) + 8 * (r >> 2) + 4 * hh;
        const float inv = RCP(L[r]);
        obase[(size_t)qr * 4096] = f2bf_rne(O0[r] * inv);
        obase[(size_t)qr * 4096 + 32] = f2bf_rne(O1[r] * inv);
    }
}

extern "C" void kernel_launch(void* const* d_in, const int* in_sizes, int n_in,
                              void* d_out, int out_size, void* d_ws, size_t ws_size,
                              hipStream_t stream) {
    const float* query = (const float*)d_in[0];
    const float* key_ = (const float*)d_in[1];
    const float* value = (const float*)d_in[2];
    const int* key_mask = (const int*)d_in[3];
    const float* Wq = (const float*)d_in[4];
    const float* bq = (const float*)d_in[5];
    const float* Wk = (const float*)d_in[6];
    const float* bk = (const float*)d_in[7];
    const float* Wv = (const float*)d_in[8];
    const float* bv = (const float*)d_in[9];
    const float* Wo = (const float*)d_in[10];
    const float* bo = (const float*)d_in[11];
    float* out = (float*)d_out;

    const size_t NE = (size_t)4096 * 1024;
    unsigned short* q_ws = (unsigned short*)d_ws;
    unsigned short* k_ws = q_ws + NE;
    unsigned short* v_ws = k_ws + NE;
    unsigned short* a_ws = v_ws + NE;
    unsigned short* wt_ws = a_ws + NE;

    transpose_w<<<dim3(16, 16, 4), 256, 0, stream>>>(Wq, Wk, Wv, Wo, wt_ws);
    qkv_gemm<<<dim3(8, 32, 3), 256, 0, stream>>>(query, key_, value, wt_ws,
                                                 bq, bk, bv, q_ws, k_ws, v_ws);
    attn_kernel<<<dim3(8, 4, 16), 256, 0, stream>>>(q_ws, k_ws, v_ws, key_mask, a_ws);
    out_gemm<<<dim3(8, 32, 1), 256, 0, stream>>>(a_ws, wt_ws, bo, out);
}